// Round 5
// baseline (153.508 us; speedup 1.0000x reference)
//
#include <hip/hip_runtime.h>

// InvButterflyLayer: B=256, MID=16384, OUT=16384, C=16, NLVL=8.
// Live cone: level lvl only needs t < 2^(8-lvl); level 0 t<256 -> x[0:8224).
//
// Kernel A: block=(i,b) [dim3(2,256) x 256 thr]. Levels 0..3. LDS = state only
//   (2x16KB ping-pong). Weights from global (uniform per wave -> broadcast,
//   L1/L2-hot). Writes S3[bi=2b+i][vec=n3*32+t][16] to d_ws.
// Kernel B: block=(n4,chunk) [dim3(16,32) x 256 thr], bi-chunk of 16.
//   Stages lvl3 parents (512 vec = 32KB, correctly sized: 32t x 16bi),
//   levels 4..8 ping-pong (bufN 16KB), then 16->64 dense + complex recombine
//   with FE from global. R4's stage-overflow race is fixed by sizing bufP.
//
// LDS swizzle (verified R3/R4: SQ_LDS_BANK_CONFLICT=0): vector v = 4 float4
// chunks; chunk q at (v>>1)*32 + ((((v&1)<<2)|q) ^ ((v>>1 ^ v>>4)&7))*4.

#define OUT_HALF 2097152

__device__ __forceinline__ int paddr(int v, int q) {
    const int h    = v >> 1;
    const int slot = ((v & 1) << 2) | q;
    const int swz  = (h ^ (h >> 3)) & 7;
    return (h << 5) + ((slot ^ swz) << 2);
}

__device__ __forceinline__ void fma16(float* acc, float p, const float* w) {
#pragma unroll
    for (int d = 0; d < 16; d++) acc[d] += p * w[d];
}

__device__ __forceinline__ void store_relu(float* base, int v, const float* acc) {
#pragma unroll
    for (int q = 0; q < 4; q++) {
        *(float4*)(base + paddr(v, q)) =
            make_float4(fmaxf(acc[4 * q + 0], 0.f), fmaxf(acc[4 * q + 1], 0.f),
                        fmaxf(acc[4 * q + 2], 0.f), fmaxf(acc[4 * q + 3], 0.f));
    }
}

__global__ __launch_bounds__(256, 4)
void ibf_A(const float* __restrict__ in_data,
           const float* __restrict__ mid_dense,
           const float* __restrict__ in_filter,
           const float* __restrict__ in_bias,
           const float* __restrict__ filters,
           const float* __restrict__ biases,
           float* __restrict__ S3) {
    __shared__ __align__(16) float buf0[4096];   // 256 vec
    __shared__ __align__(16) float buf1[4096];

    const int tid = threadIdx.x;
    const int i   = blockIdx.x;
    const int b   = blockIdx.y;

    // ---- level 0: t = tid, 64-tap window at stride 32 ----
    {
        float acc[16];
#pragma unroll
        for (int c = 0; c < 16; c++) acc[c] = in_bias[c];
        const float4* inb = (const float4*)(in_data + ((size_t)b * 16384 + (size_t)32 * tid) * 2);
        const float4* mdb = (const float4*)(mid_dense + (size_t)(32 * tid) * 2);
#pragma unroll 4
        for (int w2 = 0; w2 < 32; w2++) {
            float4 iv = inb[w2];
            float4 mv = mdb[w2];
            float x0 = (i == 0) ? iv.x * mv.x : iv.y * mv.y;
            float x1 = (i == 0) ? iv.z * mv.z : iv.w * mv.w;
            const float* F0 = in_filter + w2 * 32;   // block-uniform -> L1 broadcast
            fma16(acc, x0, F0);
            fma16(acc, x1, F0 + 16);
        }
        store_relu(buf0, tid, acc);
    }
    __syncthreads();

    // ---- levels 1..3: weights from global (wave-uniform / 2-way) ----
    float* P = buf0;
    float* N = buf1;
#pragma unroll
    for (int lvl = 1; lvl <= 3; lvl++) {
        const int sh = 8 - lvl;
        const int T  = 1 << sh;
        const int n  = tid >> sh;
        const int t  = tid & (T - 1);
        const float* Wn = filters + (size_t)(lvl - 1) * 131072 + (size_t)n * 512;
        const float* bn = biases + (size_t)(lvl - 1) * 4096 + n * 16;
        float acc[16];
#pragma unroll
        for (int qb = 0; qb < 4; qb++) {
            float4 bv = *(const float4*)(bn + 4 * qb);
            acc[4*qb] = bv.x; acc[4*qb+1] = bv.y; acc[4*qb+2] = bv.z; acc[4*qb+3] = bv.w;
        }
        const int pb = (n >> 1) << (sh + 1);
#pragma unroll
        for (int k = 0; k < 2; k++) {
            const int pv = pb + 2 * t + k;
#pragma unroll
            for (int cq = 0; cq < 4; cq++) {
                float4 pc = *(const float4*)(P + paddr(pv, cq));
                const float* w0 = Wn + k * 256 + cq * 64;
                fma16(acc, pc.x, w0);
                fma16(acc, pc.y, w0 + 16);
                fma16(acc, pc.z, w0 + 32);
                fma16(acc, pc.w, w0 + 48);
            }
        }
        if (lvl < 3) {
            store_relu(N, tid, acc);
            __syncthreads();
            float* tmp = P; P = N; N = tmp;
        } else {
            float* dst = S3 + ((size_t)(2 * b + i) * 256 + tid) * 16;
#pragma unroll
            for (int qd = 0; qd < 4; qd++) {
                ((float4*)dst)[qd] = make_float4(fmaxf(acc[4*qd], 0.f), fmaxf(acc[4*qd+1], 0.f),
                                                 fmaxf(acc[4*qd+2], 0.f), fmaxf(acc[4*qd+3], 0.f));
            }
        }
    }
}

__global__ __launch_bounds__(256, 4)
void ibf_B(const float* __restrict__ filters,
           const float* __restrict__ biases,
           const float* __restrict__ fea_dense,
           const float* __restrict__ S3,
           float* __restrict__ out) {
    __shared__ __align__(16) float bufP[8192];   // up to 512 vec (lvl3 parents)
    __shared__ __align__(16) float bufN[4096];   // up to 256 vec

    const int tid   = threadIdx.x;
    const int n4    = blockIdx.x;   // 0..15
    const int chunk = blockIdx.y;   // 0..31
    const int bi0   = chunk * 16;
    const int n3    = n4 >> 1;

    // ---- stage lvl3 parents: 32 t x 16 bi = 512 vec (fits bufP!) ----
    for (int idx = tid; idx < 2048; idx += 256) {
        const int bi_l = idx >> 7;          // 0..15
        const int r    = idx & 127;
        const int t3   = r >> 2;            // 0..31
        const int q    = r & 3;
        float4 v = *(const float4*)(S3 + ((size_t)(bi0 + bi_l) * 256 + n3 * 32 + t3) * 16 + 4 * q);
        *(float4*)(bufP + paddr(t3 * 16 + bi_l, q)) = v;
    }
    __syncthreads();

    // ---- levels 4..8: ping-pong; weights from global ----
    float* P = bufP;
    float* N = bufN;
#pragma unroll
    for (int lvl = 4; lvl <= 8; lvl++) {
        const int Tsh   = 8 - lvl;                    // 4,3,2,1,0
        const int n_loc = tid >> (Tsh + 4);
        const int t     = (tid >> 4) & ((1 << Tsh) - 1);
        const int bi    = tid & 15;
        const int gn    = (lvl - 1) * 256 + (n4 << (lvl - 4)) + n_loc;
        const float* Wn = filters + (size_t)gn * 512;
        const float* bn = biases + (size_t)gn * 16;
        float acc[16];
#pragma unroll
        for (int qb = 0; qb < 4; qb++) {
            float4 bv = *(const float4*)(bn + 4 * qb);
            acc[4*qb] = bv.x; acc[4*qb+1] = bv.y; acc[4*qb+2] = bv.z; acc[4*qb+3] = bv.w;
        }
        const int pb = (n_loc >> 1) << (Tsh + 5);     // parent node * (2T*16)
#pragma unroll
        for (int k = 0; k < 2; k++) {
            const int pv = pb + (2 * t + k) * 16 + bi;
#pragma unroll
            for (int cq = 0; cq < 4; cq++) {
                float4 pc = *(const float4*)(P + paddr(pv, cq));
                const float* w0 = Wn + k * 256 + cq * 64;
                fma16(acc, pc.x, w0);
                fma16(acc, pc.y, w0 + 16);
                fma16(acc, pc.z, w0 + 32);
                fma16(acc, pc.w, w0 + 48);
            }
        }
        store_relu(N, tid, acc);
        __syncthreads();
        float* tmp = P; P = N; N = tmp;
    }
    // after 5 swaps feat (lvl8: vec = n8l*16 + bi, 256 vec) is in bufN... swaps:
    // lvl4 N=bufN, lvl5 N=bufP, lvl6 N=bufN, lvl7 N=bufP, lvl8 N=bufN -> P=bufN now.

    // ---- dense 16->64 + complex recombine; FE from global ----
    // thread = (n8l = tid>>4, bpp = (tid>>2)&3, uq = tid&3): b-pair, 8 j's
    {
        const int n8l = tid >> 4;
        const int bpp = (tid >> 2) & 3;
        const int uq  = tid & 3;
        const int n8g = n4 * 16 + n8l;
        const float* fj = fea_dense + (size_t)n8g * 1024 + uq * 16;
        float r0a[8], r1a[8], i1a[8], r0b[8], r1b[8], i1b[8];
#pragma unroll
        for (int j = 0; j < 8; j++) {
            r0a[j] = 0.f; r1a[j] = 0.f; i1a[j] = 0.f;
            r0b[j] = 0.f; r1b[j] = 0.f; i1b[j] = 0.f;
        }
#pragma unroll
        for (int cq = 0; cq < 4; cq++) {
            // feat vectors: bi = 4*bpp + {0:(b_e,i0), 1:(b_e,i1), 2:(b_o,i0), 3:(b_o,i1)}
            float pch[4][4];
#pragma unroll
            for (int vv = 0; vv < 4; vv++) {
                float4 x = *(const float4*)(P + paddr(n8l * 16 + 4 * bpp + vv, cq));
                pch[vv][0] = x.x; pch[vv][1] = x.y; pch[vv][2] = x.z; pch[vv][3] = x.w;
            }
#pragma unroll
            for (int cc = 0; cc < 4; cc++) {
                const int c = 4 * cq + cc;
                const float* wr = fj + c * 64;
                float4 wa = *(const float4*)(wr);
                float4 wb = *(const float4*)(wr + 4);
                float4 wc = *(const float4*)(wr + 8);
                float4 wd = *(const float4*)(wr + 12);
                const float we[8] = {wa.x, wa.z, wb.x, wb.z, wc.x, wc.z, wd.x, wd.z};
                const float wo[8] = {wa.y, wa.w, wb.y, wb.w, wc.y, wc.w, wd.y, wd.w};
                float fe0 = pch[0][cc], fo0 = pch[1][cc];
                float fe1 = pch[2][cc], fo1 = pch[3][cc];
#pragma unroll
                for (int j = 0; j < 8; j++) {
                    r0a[j] += fe0 * we[j];  r1a[j] += fe0 * wo[j];  i1a[j] += fo0 * wo[j];
                    r0b[j] += fe1 * we[j];  r1b[j] += fe1 * wo[j];  i1b[j] += fo1 * wo[j];
                }
            }
        }
        const int b0 = chunk * 8 + 2 * bpp;
#pragma unroll
        for (int pp = 0; pp < 2; pp++) {
            const float* r0 = pp ? r0b : r0a;
            const float* r1 = pp ? r1b : r1a;
            const float* i1 = pp ? i1b : i1a;
            float* o0p = out + (size_t)(b0 + pp) * 8192 + n8g * 32 + uq * 8;
            float* o1p = o0p + OUT_HALF;
            *(float4*)(o0p)     = make_float4((r0[0] - i1[0]) * (1.f / 16384.f), (r0[1] - i1[1]) * (1.f / 16384.f),
                                              (r0[2] - i1[2]) * (1.f / 16384.f), (r0[3] - i1[3]) * (1.f / 16384.f));
            *(float4*)(o0p + 4) = make_float4((r0[4] - i1[4]) * (1.f / 16384.f), (r0[5] - i1[5]) * (1.f / 16384.f),
                                              (r0[6] - i1[6]) * (1.f / 16384.f), (r0[7] - i1[7]) * (1.f / 16384.f));
            *(float4*)(o1p)     = make_float4(r1[0], r1[1], r1[2], r1[3]);
            *(float4*)(o1p + 4) = make_float4(r1[4], r1[5], r1[6], r1[7]);
        }
    }
}

extern "C" void kernel_launch(void* const* d_in, const int* in_sizes, int n_in,
                              void* d_out, int out_size, void* d_ws, size_t ws_size,
                              hipStream_t stream) {
    const float* in_data   = (const float*)d_in[0];
    const float* mid_dense = (const float*)d_in[1];
    const float* in_filter = (const float*)d_in[2];
    const float* in_bias   = (const float*)d_in[3];
    const float* filters   = (const float*)d_in[4];
    const float* biases    = (const float*)d_in[5];
    const float* fea_dense = (const float*)d_in[6];
    float* out = (float*)d_out;
    float* S3  = (float*)d_ws;   // 512 bi x 256 vec x 16 floats = 8 MB

    ibf_A<<<dim3(2, 256), 256, 0, stream>>>(in_data, mid_dense, in_filter, in_bias,
                                            filters, biases, S3);
    ibf_B<<<dim3(16, 32), 256, 0, stream>>>(filters, biases, fea_dense, S3, out);
}

// Round 7
// 40.310 us; speedup vs baseline: 3.8082x; 3.8082x over previous
//
#include <hip/hip_runtime.h>

// InvButterflyLayer via MFMA (bf16 in, fp32 accum). B=256, MID=16384, C=16.
// Live cone: level lvl needs t < 2^(8-lvl); lvl0 t<256 -> x[0:8224).
//
// Formulation: each level/node is [rows x 32] * [32 x 16] with rows=(bi,t),
// K = 2 parents x 16 ch ordered k2 = 2c + parity. One 16x16x32 MFMA per
// 16-row tile. D regs (4 consecutive rows, fixed col d) pack into 2 b32
// bf16-pair writes at [row2=r>>1][k2=2d+(r&1)] -> builds next level's A.
// Weights staged transposed [node][d][k2] bf16 -> B-frag = one b128 (4 VGPR).
// All state/weight LDS accesses go through pure-function XOR swizzle fsw().
//
// R7 fixes vs R6: lvl8 covers all 16 planes (at<16); AF planes = 512B with
// full-offset fsw both sides (was 1024B stride overflowing into W + base
// mismatch); dense covers all 32 n8 (q<8).

#define OUT_HALF 2097152

typedef __attribute__((ext_vector_type(4))) float f32x4;
typedef __attribute__((ext_vector_type(8))) short s16x8;

__device__ __forceinline__ uint fsw(uint a) {
    return a ^ ((((a >> 6) ^ (a >> 8)) & 3u) << 4);
}
__device__ __forceinline__ ushort bfr(float f) {   // f32 -> bf16 RNE
    uint u = __float_as_uint(f);
    return (ushort)((u + 0x7FFFu + ((u >> 16) & 1u)) >> 16);
}
__device__ __forceinline__ uint pk(float a, float b) {
    return (uint)bfr(a) | ((uint)bfr(b) << 16);
}

// Generic tree level: A[plane p][16-row tiles] x W[child] -> next A.
// planes = 2^lgNP node-planes (x2 i-planes in phase A, folded into p's high bits).
__device__ __forceinline__ void tree_level(
    char* smb, const int lane, const int wave,
    uint AOff, uint NOff, int lgR, int lgNP, int nTiles,
    uint WOff, int wnb, uint LBOff, int bnb)
{
    const int m  = lane & 15;
    const int kg = lane >> 4;
    const int lgTPP = lgR - 4;
    for (int at = wave; at < nTiles; at += 4) {
        const int p  = at >> lgTPP;
        const int tc = at & ((1 << lgTPP) - 1);
        const int np = p & ((1 << lgNP) - 1);
        const int ii = p >> lgNP;
        s16x8 af = *(const s16x8*)(smb + AOff + (p << (lgR + 6)) +
                                   fsw((uint)((tc * 16 + m) * 64 + kg * 16)));
#pragma unroll
        for (int sib = 0; sib < 2; sib++) {
            const int nl = 2 * np + sib;
            s16x8 bf = *(const s16x8*)(smb + WOff +
                         fsw((uint)((wnb + nl) * 1024 + m * 64 + kg * 16)));
            float bv = *(const float*)(smb + LBOff + ((bnb + nl) * 16 + m) * 4);
            f32x4 acc = {bv, bv, bv, bv};
            acc = __builtin_amdgcn_mfma_f32_16x16x32_bf16(af, bf, acc, 0, 0, 0);
            const int p2 = (ii << (lgNP + 1)) + nl;
            const uint wb = NOff + (p2 << (lgR + 5));
            const int r2 = tc * 8 + kg * 2;
            *(uint*)(smb + wb + fsw((uint)(r2 * 64 + m * 4))) =
                pk(fmaxf(acc.x, 0.f), fmaxf(acc.y, 0.f));
            *(uint*)(smb + wb + fsw((uint)((r2 + 1) * 64 + m * 4))) =
                pk(fmaxf(acc.z, 0.f), fmaxf(acc.w, 0.f));
        }
    }
}

// LDS map A (bytes): X0@0[8256] X1@8256[8256] | A2@0[8192] A3@8256[8192]
//                    A1@16512[8192] W@24704[14336] BT0@39040[2048] LB@41088[960]
__global__ __launch_bounds__(256, 3)
void ibf_A(const float* __restrict__ in_data, const float* __restrict__ mid_dense,
           const float* __restrict__ in_filter, const float* __restrict__ in_bias,
           const float* __restrict__ filters, const float* __restrict__ biases,
           uint* __restrict__ S3)
{
    __shared__ __align__(16) char smb[42048];
    const int tid = threadIdx.x, lane = tid & 63, wave = tid >> 6;
    const int b = blockIdx.x, th = blockIdx.y;

    // stage x = in_data*mid (m in [th*4096, th*4096+4128)) -> X0/X1 bf16
    {
        const float4* inb = (const float4*)in_data + (size_t)b * 8192 + th * 2048;
        const float4* mdb = (const float4*)mid_dense + th * 2048;
        for (int mp = tid; mp < 2064; mp += 256) {
            float4 iv = inb[mp], mv = mdb[mp];
            *(uint*)(smb + 0    + fsw((uint)(mp * 4))) = pk(iv.x * mv.x, iv.z * mv.z);
            *(uint*)(smb + 8256 + fsw((uint)(mp * 4))) = pk(iv.y * mv.y, iv.w * mv.w);
        }
    }
    // stage lvl1-3 weights: W[nidx][d][k2=2c+par] bf16
    for (int t = tid; t < 3584; t += 256) {
        int nidx = t >> 8, r = t & 255, d = r & 15, c = r >> 4;
        int lvl = (nidx < 2) ? 1 : ((nidx < 6) ? 2 : 3);
        int n = nidx - ((1 << lvl) - 2);
        const float* src = filters + (size_t)(lvl - 1) * 131072 + n * 512 + c * 16 + d;
        *(uint*)(smb + 24704 + fsw((uint)(nidx * 1024 + d * 64 + c * 4))) = pk(src[0], src[256]);
    }
    // stage in_filter: BT0[c][w] bf16 (plain k-order)
    for (int t = tid; t < 512; t += 256) {
        int c = t >> 5, w2 = t & 31;
        *(uint*)(smb + 39040 + fsw((uint)(c * 128 + w2 * 4))) =
            pk(in_filter[(2 * w2) * 16 + c], in_filter[(2 * w2 + 1) * 16 + c]);
    }
    // stage biases f32: nidx 0..13 tree, 224.. = in_bias
    if (tid < 240) {
        float v;
        if (tid < 224) {
            int nidx = tid >> 4;
            int lvl = (nidx < 2) ? 1 : ((nidx < 6) ? 2 : 3);
            int n = nidx - ((1 << lvl) - 2);
            v = biases[(size_t)(lvl - 1) * 4096 + n * 16 + (tid & 15)];
        } else v = in_bias[tid - 224];
        *(float*)(smb + 41088 + tid * 4) = v;
    }
    __syncthreads();

    // lvl0: A[t][w=64] (x windows) x BT0 -> A1 (2 i-planes x 64 row2 x 64B)
    {
        const int m = lane & 15, kg = lane >> 4;
        s16x8 b0 = *(const s16x8*)(smb + 39040 + fsw((uint)(m * 128 + kg * 16)));
        s16x8 b1 = *(const s16x8*)(smb + 39040 + fsw((uint)(m * 128 + 64 + kg * 16)));
        float bv = *(const float*)(smb + 41088 + (224 + m) * 4);
        for (int at = wave; at < 16; at += 4) {
            int i = at >> 3, tc = at & 7;
            uint xb = i ? 8256u : 0u;
            s16x8 a0 = *(const s16x8*)(smb + xb + fsw((uint)((tc * 16 + m) * 64 + kg * 16)));
            s16x8 a1 = *(const s16x8*)(smb + xb + fsw((uint)((tc * 16 + m) * 64 + 64 + kg * 16)));
            f32x4 acc = {bv, bv, bv, bv};
            acc = __builtin_amdgcn_mfma_f32_16x16x32_bf16(a0, b0, acc, 0, 0, 0);
            acc = __builtin_amdgcn_mfma_f32_16x16x32_bf16(a1, b1, acc, 0, 0, 0);
            uint wb = 16512u + (uint)i * 4096u;
            int r2 = tc * 8 + kg * 2;
            *(uint*)(smb + wb + fsw((uint)(r2 * 64 + m * 4))) =
                pk(fmaxf(acc.x, 0.f), fmaxf(acc.y, 0.f));
            *(uint*)(smb + wb + fsw((uint)((r2 + 1) * 64 + m * 4))) =
                pk(fmaxf(acc.z, 0.f), fmaxf(acc.w, 0.f));
        }
    }
    __syncthreads();
    tree_level(smb, lane, wave, 16512, 0,    6, 0, 8, 24704, 0, 41088, 0);  // lvl1
    __syncthreads();
    tree_level(smb, lane, wave, 0,     8256, 5, 1, 8, 24704, 2, 41088, 2);  // lvl2
    __syncthreads();
    // lvl3 -> S3 global, bf16 pairs
    {
        const int m = lane & 15, kg = lane >> 4;
        for (int at = wave; at < 8; at += 4) {
            int np = at & 3, i = at >> 2;
            s16x8 af = *(const s16x8*)(smb + 8256 + (at << 10) + fsw((uint)(m * 64 + kg * 16)));
#pragma unroll
            for (int sib = 0; sib < 2; sib++) {
                int n3 = 2 * np + sib;
                s16x8 bf = *(const s16x8*)(smb + 24704 +
                             fsw((uint)((6 + n3) * 1024 + m * 64 + kg * 16)));
                float bv = *(const float*)(smb + 41088 + ((6 + n3) * 16 + m) * 4);
                f32x4 acc = {bv, bv, bv, bv};
                acc = __builtin_amdgcn_mfma_f32_16x16x32_bf16(af, bf, acc, 0, 0, 0);
                int bi = 2 * b + i;
                int t4 = th * 8 + kg * 2;
                uint idx = ((uint)(n3 * 512 + bi) * 16 + t4) * 16 + m;
                S3[idx]      = pk(fmaxf(acc.x, 0.f), fmaxf(acc.y, 0.f));
                S3[idx + 16] = pk(fmaxf(acc.z, 0.f), fmaxf(acc.w, 0.f));
            }
        }
    }
}

// LDS map B (bytes): P0@0[8192] P1@8192[8192] AF@16384[16384] W@32768[32768] LB@65536[3968]
__global__ __launch_bounds__(256, 2)
void ibf_B(const float* __restrict__ filters, const float* __restrict__ biases,
           const float* __restrict__ fea_dense, const uint* __restrict__ S3,
           float* __restrict__ out)
{
    __shared__ __align__(16) char smb[69504];
    const int tid = threadIdx.x, lane = tid & 63, wave = tid >> 6;
    const int n3 = blockIdx.x, chunk = blockIdx.y;

    // zero A_f (so padded K 16..31 of valid rows are 0)
    for (int o = tid * 16; o < 16384; o += 4096)
        *(float4*)(smb + 16384 + o) = make_float4(0.f, 0.f, 0.f, 0.f);
    // stage A4 from S3 (direct byte-image copy with dest swizzle)
    {
        const char* src = (const char*)S3 + ((size_t)n3 * 512 + chunk * 8) * 1024;
        for (int ci = tid; ci < 512; ci += 256)
            *(float4*)(smb + fsw((uint)(ci * 16))) = *(const float4*)(src + ci * 16);
    }
    // stage biases (62 nodes, level-concat)
    for (int t = tid; t < 992; t += 256) {
        int nidx = t >> 4, q = nidx + 2;
        int l3 = 31 - __clz(q);
        int nl = q - (1 << l3);
        int gn = (n3 << l3) + nl;
        *(float*)(smb + 65536 + t * 4) = biases[(size_t)(l3 + 2) * 4096 + gn * 16 + (t & 15)];
    }
    // per-level weight staging into shared W region
    auto stage_w = [&](int l3) {
        int NL = 1 << l3;
        const float* fb = filters + (size_t)(l3 + 2) * 131072;
        for (int t = tid; t < NL * 256; t += 256) {
            int nl = t >> 8, r = t & 255, d = r & 15, c = r >> 4;
            const float* src = fb + (size_t)((n3 << l3) + nl) * 512 + c * 16 + d;
            *(uint*)(smb + 32768 + fsw((uint)(nl * 1024 + d * 64 + c * 4))) = pk(src[0], src[256]);
        }
    };
    stage_w(1);
    __syncthreads();
    tree_level(smb, lane, wave, 0,    8192, 7, 0, 8, 32768, 0, 65536, 0);   // lvl4
    __syncthreads();
    stage_w(2);
    __syncthreads();
    tree_level(smb, lane, wave, 8192, 0,    6, 1, 8, 32768, 0, 65536, 2);   // lvl5
    __syncthreads();
    stage_w(3);
    __syncthreads();
    tree_level(smb, lane, wave, 0,    8192, 5, 2, 8, 32768, 0, 65536, 6);   // lvl6
    __syncthreads();
    stage_w(4);
    __syncthreads();
    tree_level(smb, lane, wave, 8192, 0,    4, 3, 8, 32768, 0, 65536, 14);  // lvl7 -> A8 flat @P0
    __syncthreads();
    stage_w(5);
    __syncthreads();
    // lvl8: 16 n7-planes (8 rows each = bi); D rows 8..15 discarded.
    // feat -> AF: 32 planes x 512B (8 rows x 64B), fsw over FULL offset.
    {
        const int m = lane & 15, kg = lane >> 4;
        for (int at = wave; at < 16; at += 4) {
            s16x8 af = *(const s16x8*)(smb + at * 512 + fsw((uint)(m * 64 + kg * 16)));
#pragma unroll
            for (int sib = 0; sib < 2; sib++) {
                int nl = 2 * at + sib;
                s16x8 bf = *(const s16x8*)(smb + 32768 +
                             fsw((uint)(nl * 1024 + m * 64 + kg * 16)));
                float bv = *(const float*)(smb + 65536 + ((30 + nl) * 16 + m) * 4);
                f32x4 acc = {bv, bv, bv, bv};
                acc = __builtin_amdgcn_mfma_f32_16x16x32_bf16(af, bf, acc, 0, 0, 0);
                if (kg < 2) {
                    float v[4] = {fmaxf(acc.x, 0.f), fmaxf(acc.y, 0.f),
                                  fmaxf(acc.z, 0.f), fmaxf(acc.w, 0.f)};
#pragma unroll
                    for (int j = 0; j < 4; j++) {
                        uint o = (uint)(nl * 512 + (kg * 4 + j) * 64 + m * 2);
                        *(ushort*)(smb + 16384 + fsw(o)) = bfr(v[j]);
                    }
                }
            }
        }
    }
    __syncthreads();
    // dense 16->64 (K padded to 32) + complex recombine; all 32 n8 per block
    {
        const int m = lane & 15, kg = lane >> 4;
        for (int q = 0; q < 8; q++) {
            int n8l = wave * 8 + q;
            int gn8 = n3 * 32 + n8l;
            s16x8 af = *(const s16x8*)(smb + 16384 +
                         fsw((uint)(n8l * 512 + m * 64 + kg * 16)));
            const float* fb = fea_dense + (size_t)gn8 * 1024;
#pragma unroll
            for (int ut = 0; ut < 4; ut++) {
                s16x8 bf = {0, 0, 0, 0, 0, 0, 0, 0};
                if (kg < 2) {
                    const float* fp = fb + kg * 512 + ut * 16 + m;
                    bf[0] = (short)bfr(fp[0]);   bf[1] = (short)bfr(fp[64]);
                    bf[2] = (short)bfr(fp[128]); bf[3] = (short)bfr(fp[192]);
                    bf[4] = (short)bfr(fp[256]); bf[5] = (short)bfr(fp[320]);
                    bf[6] = (short)bfr(fp[384]); bf[7] = (short)bfr(fp[448]);
                }
                f32x4 acc = {0.f, 0.f, 0.f, 0.f};
                acc = __builtin_amdgcn_mfma_f32_16x16x32_bf16(af, bf, acc, 0, 0, 0);
                float s0 = __shfl_xor(acc.y, 1);
                float s2 = __shfl_xor(acc.w, 1);
                if (kg < 2) {
                    int g = gn8 * 32 + ut * 8 + (m >> 1);
                    bool odd = (m & 1);
                    float v0 = odd ? acc.x : (acc.x - s0) * (1.f / 16384.f);
                    float v1 = odd ? acc.z : (acc.z - s2) * (1.f / 16384.f);
                    size_t off = (odd ? (size_t)OUT_HALF : (size_t)0) + (size_t)g;
                    int b0 = chunk * 4 + kg * 2;
                    out[(size_t)b0 * 8192 + off]       = v0;
                    out[(size_t)(b0 + 1) * 8192 + off] = v1;
                }
            }
        }
    }
}

extern "C" void kernel_launch(void* const* d_in, const int* in_sizes, int n_in,
                              void* d_out, int out_size, void* d_ws, size_t ws_size,
                              hipStream_t stream) {
    const float* in_data   = (const float*)d_in[0];
    const float* mid_dense = (const float*)d_in[1];
    const float* in_filter = (const float*)d_in[2];
    const float* in_bias   = (const float*)d_in[3];
    const float* filters   = (const float*)d_in[4];
    const float* biases    = (const float*)d_in[5];
    const float* fea_dense = (const float*)d_in[6];
    float* out = (float*)d_out;
    uint* S3   = (uint*)d_ws;   // S3[8 n3][512 bi][16 t4][16 uint] bf16-pairs = 4 MB

    ibf_A<<<dim3(256, 2), 256, 0, stream>>>(in_data, mid_dense, in_filter, in_bias,
                                            filters, biases, S3);
    ibf_B<<<dim3(8, 64), 256, 0, stream>>>(filters, biases, fea_dense, S3, out);
}